// Round 1
// baseline (2541.870 us; speedup 1.0000x reference)
//
#include <hip/hip_runtime.h>
#include <stdint.h>

#define NN 20000
#define DD 16
#define FF 128
#define GG 512   // 4*F

typedef _Float16 h16;
typedef _Float16 half8 __attribute__((ext_vector_type(8)));
typedef float f32x4 __attribute__((ext_vector_type(4)));

// ---- workspace layout (bytes, all 256-aligned) ----
#define OFF_X    0u          // x_f16   [N][128]          5,120,000
#define OFF_H1   5120000u    // h1_f16  [N][128]          5,120,000
#define OFF_N1   10240000u   // n1buf   [2][N][128] f16  10,240,000
#define OFF_N2   20480000u   // n2buf   [2][N][128] f16  10,240,000
#define OFF_B1   30720000u   // Bpack   [4sets][8kc][32ct][64lane][8] f16 (sets 0,1=l1; 2,3=l2)
#define OFF_WC1  31768576u   // Cpack   [12][8][64][8] f16
#define OFF_WC2  31866880u   // Wcat2   [384][2] f32
#define OFF_BI1  31869952u   // bias1   [2][512] f32
#define OFF_BI2  31874048u   // bias2   [2][512] f32
#define OFF_BS1  31878144u   // bs1     [128] f32
#define OFF_B2S  31878656u   // b2s     [2] f32

__device__ __forceinline__ float sigm(float x)  { return __builtin_amdgcn_rcpf(1.f + __expf(-x)); }
__device__ __forceinline__ float tanh_(float x) { return 2.f * __builtin_amdgcn_rcpf(1.f + __expf(-2.f * x)) - 1.f; }

// A-fragment loader from swizzled [64][128] f16 LDS tile.
// Fragment k-map (consistent with B pack): k = kcL*32 + (lg<<2) + (j&3) + 16*(j>>2)
__device__ __forceinline__ half8 load_afrag(const unsigned short* Asrc, int rowbase,
                                            int ll, int lg, int kcL) {
    int row = rowbase + ll;
    int sw  = (row & 7) << 4;
    int k0b = (kcL * 32 + (lg << 2)) * 2;
    const char* base = (const char*)Asrc + row * 256;
    uint2 lo = *(const uint2*)(base + (k0b ^ sw));
    uint2 hi = *(const uint2*)(base + ((k0b + 32) ^ sw));
    union { uint4 u; half8 h; } cv;
    cv.u = make_uint4(lo.x, lo.y, hi.x, hi.y);
    return cv.h;
}

// ---------------- prep kernels ----------------
__global__ void k_cast_x(const float* __restrict__ x, h16* __restrict__ xo, int n) {
    int i = blockIdx.x * blockDim.x + threadIdx.x;
    int base = i * 8;
    if (base >= n) return;
    const float4* p = (const float4*)(x + base);
    float4 a = p[0], b = p[1];
    half8 v = {(h16)a.x,(h16)a.y,(h16)a.z,(h16)a.w,(h16)b.x,(h16)b.y,(h16)b.z,(h16)b.w};
    *(half8*)(xo + base) = v;
}

// pack [x|h] gate weights into per-lane fragment order: [set][kc][ctg][lane][8]
__global__ void k_pack_gates(const float* __restrict__ l1Wih, const float* __restrict__ l1Whh,
                             const float* __restrict__ l2Wih, const float* __restrict__ l2Whh,
                             h16* __restrict__ Bp) {
    int idx = blockIdx.x * 256 + threadIdx.x;      // 65536 total
    int set = idx >> 14;
    int rem = idx & 16383;
    int kc  = rem >> 11;
    int ct  = (rem >> 6) & 31;
    int l   = rem & 63;
    const float* Wih = (set < 2 ? l1Wih : l2Wih) + (size_t)(set & 1) * (FF * GG);
    const float* Whh = (set < 2 ? l1Whh : l2Whh) + (size_t)(set & 1) * (FF * GG);
    int col = ct * 16 + (l & 15);
    half8 v;
#pragma unroll
    for (int j = 0; j < 8; j++) {
        int k = kc * 32 + ((l >> 4) << 2) + (j & 3) + ((j >> 2) << 4);
        float val = (k < FF) ? Wih[k * GG + col] : Whh[(k - FF) * GG + col];
        v[j] = (h16)val;
    }
    *(half8*)(Bp + (size_t)idx * 8) = v;
}

// pack layer-1 combine weights: concat [x|n0|n1] (K=384) x 128, with 0.5 averaging folded in
__global__ void k_pack_wc1(const float* __restrict__ Wself, const float* __restrict__ Wneigh,
                           h16* __restrict__ Cp) {
    int idx = blockIdx.x * 256 + threadIdx.x;      // 6144 total
    if (idx >= 6144) return;
    int kc = idx >> 9;
    int ct = (idx >> 6) & 7;
    int l  = idx & 63;
    int col = ct * 16 + (l & 15);
    half8 v;
#pragma unroll
    for (int j = 0; j < 8; j++) {
        int k = kc * 32 + ((l >> 4) << 2) + (j & 3) + ((j >> 2) << 4);
        float val;
        if (k < 128)      val = 0.5f * (Wself[k * 128 + col] + Wself[16384 + k * 128 + col]);
        else if (k < 256) val = 0.5f * Wneigh[(k - 128) * 128 + col];
        else              val = 0.5f * Wneigh[16384 + (k - 256) * 128 + col];
        v[j] = (h16)val;
    }
    *(half8*)(Cp + (size_t)idx * 8) = v;
}

__global__ void k_small(const float* __restrict__ l1bih, const float* __restrict__ l1bhh,
                        const float* __restrict__ l2bih, const float* __restrict__ l2bhh,
                        const float* __restrict__ l1b,  const float* __restrict__ l2Ws,
                        const float* __restrict__ l2Wn, const float* __restrict__ l2b,
                        float* __restrict__ bias1, float* __restrict__ bias2,
                        float* __restrict__ bs1,  float* __restrict__ wc2,
                        float* __restrict__ b2s) {
    int g = blockIdx.x * 256 + threadIdx.x;        // grid 8 -> 2048
    if (g < 1024) bias1[g] = l1bih[g] + l1bhh[g];
    else if (g < 2048) { int j = g - 1024; bias2[j] = l2bih[j] + l2bhh[j]; }
    if (g < 128) bs1[g] = 0.5f * (l1b[g] + l1b[128 + g]);
    if (g < 768) {
        int k = g >> 1, c = g & 1;
        float val;
        if (k < 128)      val = 0.5f * (l2Ws[k * 2 + c] + l2Ws[256 + k * 2 + c]);
        else if (k < 256) val = 0.5f * l2Wn[(k - 128) * 2 + c];
        else              val = 0.5f * l2Wn[256 + (k - 256) * 2 + c];
        wc2[g] = val;
    }
    if (g < 2) b2s[g] = 0.5f * (l2b[g] + l2b[2 + g]);
}

// ---------------- LSTM aggregation ----------------
// grid (313, 2e), block 256 (4 waves). 64 nodes/WG; wave w owns 32-feature slice
// across all 4 gates -> in-register cell update. h captured to out at t==deg-1.
__global__ __launch_bounds__(256, 2)
void k_lstm(const h16* __restrict__ src, const int* __restrict__ nbr_g,
            const int* __restrict__ deg_g, const h16* __restrict__ Bp_g,
            const float* __restrict__ bias_g, h16* __restrict__ out_g) {
    const int e = blockIdx.y;
    const int* nbr = nbr_g + (size_t)e * NN * DD;
    const int* deg = deg_g + (size_t)e * NN;
    const h16* Bp  = Bp_g + (size_t)e * (8 * 32 * 64 * 8);
    const float* bias = bias_g + e * GG;
    h16* outp = out_g + (size_t)e * NN * FF;

    __shared__ unsigned short Ax[64 * 128];   // swizzled x_t tile
    __shared__ unsigned short Ah[64 * 128];   // swizzled h tile
    __shared__ int nbr_l[64 * DD];

    const int tid = threadIdx.x;
    const int l = tid & 63, w = tid >> 6;
    const int lg = l >> 4, ll = l & 15;
    const int node0 = blockIdx.x * 64;

    for (int i = tid; i < 64 * DD; i += 256) {
        int node = node0 + (i >> 4);
        nbr_l[i] = (node < NN) ? nbr[node * DD + (i & 15)] : 0;
    }
    for (int i = tid; i < 64 * 128; i += 256) Ah[i] = 0;

    unsigned int degr4[4];                    // 4x 8-bit degree fields (255 = OOB)
#pragma unroll
    for (int rt = 0; rt < 4; rt++) {
        unsigned int pk = 0;
#pragma unroll
        for (int r = 0; r < 4; r++) {
            int node = node0 + rt * 16 + (lg << 2) + r;
            int dv = (node < NN) ? deg[node] : 255;
            pk |= ((unsigned int)(dv & 255)) << (8 * r);
        }
        degr4[rt] = pk;
    }

    float biasr[8];
#pragma unroll
    for (int ct = 0; ct < 8; ct++) {
        int gate = ct >> 1, s = ct & 1;
        biasr[ct] = bias[(gate * 8 + w * 2 + s) * 16 + ll];
    }

    f32x4 cst[4][2];
#pragma unroll
    for (int rt = 0; rt < 4; rt++)
#pragma unroll
        for (int s = 0; s < 2; s++) cst[rt][s] = (f32x4){0.f, 0.f, 0.f, 0.f};

    // deg==0 nodes output zeros
#pragma unroll
    for (int rt = 0; rt < 4; rt++)
#pragma unroll
        for (int r = 0; r < 4; r++)
            if (((degr4[rt] >> (8 * r)) & 255) == 0) {
                int node = node0 + rt * 16 + (lg << 2) + r;
#pragma unroll
                for (int s = 0; s < 2; s++)
                    outp[(size_t)node * FF + w * 32 + s * 16 + ll] = (h16)0.f;
            }

    // gather t=0 (each wave: 16 rows; swizzled 16B LDS writes)
#pragma unroll
    for (int k = 0; k < 4; k++) {
        int row = w * 16 + k * 4 + lg;
        int idx = nbr_l[row * DD + 0];
        uint4 v = *(const uint4*)(src + (size_t)idx * FF + ll * 8);
        *(uint4*)((char*)Ax + row * 256 + ((ll * 16) ^ ((row & 7) << 4))) = v;
    }
    __syncthreads();

    for (int t = 0; t < DD; t++) {
        f32x4 acc[4][8];
#pragma unroll
        for (int rt = 0; rt < 4; rt++)
#pragma unroll
            for (int ct = 0; ct < 8; ct++)
                acc[rt][ct] = (f32x4){biasr[ct], biasr[ct], biasr[ct], biasr[ct]};

#pragma unroll
        for (int kc = 0; kc < 8; kc++) {
            const unsigned short* Asrc = (kc < 4) ? Ax : Ah;
            const int kcL = kc & 3;
            half8 af[4];
#pragma unroll
            for (int rt = 0; rt < 4; rt++) af[rt] = load_afrag(Asrc, rt * 16, ll, lg, kcL);
            half8 bf[8];
#pragma unroll
            for (int ct = 0; ct < 8; ct++) {
                int gate = ct >> 1, s = ct & 1;
                int ctg = gate * 8 + w * 2 + s;
                bf[ct] = *(const half8*)(Bp + ((size_t)(kc * 32 + ctg) * 64 + l) * 8);
            }
#pragma unroll
            for (int rt = 0; rt < 4; rt++)
#pragma unroll
                for (int ct = 0; ct < 8; ct++)
                    acc[rt][ct] = __builtin_amdgcn_mfma_f32_16x16x32_f16(af[rt], bf[ct], acc[rt][ct], 0, 0, 0);
        }

        // in-register LSTM cell update; capture h at final active step
        unsigned int hn[4][4];
#pragma unroll
        for (int rt = 0; rt < 4; rt++)
#pragma unroll
            for (int r = 0; r < 4; r++) {
                unsigned int packed = 0;
                int dfield = (degr4[rt] >> (8 * r)) & 255;
#pragma unroll
                for (int s = 0; s < 2; s++) {
                    float iv = sigm(acc[rt][0 + s][r]);
                    float fv = sigm(acc[rt][2 + s][r]);
                    float gv = tanh_(acc[rt][4 + s][r]);
                    float ov = sigm(acc[rt][6 + s][r]);
                    float c_ = fv * cst[rt][s][r] + iv * gv;
                    float h_ = ov * tanh_(c_);
                    cst[rt][s][r] = c_;
                    h16 hh = (h16)h_;
                    unsigned short hb = __builtin_bit_cast(unsigned short, hh);
                    packed |= ((unsigned int)hb) << (16 * s);
                    if (t + 1 == dfield) {
                        int node = node0 + rt * 16 + (lg << 2) + r;
                        outp[(size_t)node * FF + w * 32 + s * 16 + ll] = hh;
                    }
                }
                hn[rt][r] = packed;
            }

        __syncthreads();   // all fragment reads of Ax/Ah complete

        // write new h into Ah (swizzled), launch next gather into Ax
#pragma unroll
        for (int rt = 0; rt < 4; rt++)
#pragma unroll
            for (int r = 0; r < 4; r++) {
                int row = rt * 16 + (lg << 2) + r;
                int swb = (row & 7) << 4;
                unsigned int p = hn[rt][r];
                int col0 = w * 32 + ll;
                *(unsigned short*)((char*)Ah + row * 256 + ((col0 * 2) ^ swb)) = (unsigned short)(p & 0xffff);
                *(unsigned short*)((char*)Ah + row * 256 + (((col0 + 16) * 2) ^ swb)) = (unsigned short)(p >> 16);
            }
        if (t + 1 < DD) {
#pragma unroll
            for (int k = 0; k < 4; k++) {
                int row = w * 16 + k * 4 + lg;
                int idx = nbr_l[row * DD + (t + 1)];
                uint4 v = *(const uint4*)(src + (size_t)idx * FF + ll * 8);
                *(uint4*)((char*)Ax + row * 256 + ((ll * 16) ^ ((row & 7) << 4))) = v;
            }
        }
        __syncthreads();
    }
}

// ---------------- layer-1 combine: h1 = relu([x|n0|n1] @ Wcat1 + bs1) ----------------
__global__ __launch_bounds__(256, 4)
void k_lout1(const h16* __restrict__ x16, const h16* __restrict__ n0,
             const h16* __restrict__ n1, const h16* __restrict__ Cp,
             const float* __restrict__ bs, h16* __restrict__ h1) {
    __shared__ unsigned short A3[3][64 * 128];
    const int tid = threadIdx.x;
    const int l = tid & 63, w = tid >> 6, lg = l >> 4, ll = l & 15;
    const int node0 = blockIdx.x * 64;
    const h16* srcs[3] = {x16, n0, n1};
#pragma unroll
    for (int r3 = 0; r3 < 3; r3++)
#pragma unroll
        for (int k = 0; k < 4; k++) {
            int row = w * 16 + k * 4 + lg;
            int node = node0 + row;
            uint4 v = (node < NN) ? *(const uint4*)(srcs[r3] + (size_t)node * FF + ll * 8)
                                  : make_uint4(0, 0, 0, 0);
            *(uint4*)((char*)&A3[r3][0] + row * 256 + ((ll * 16) ^ ((row & 7) << 4))) = v;
        }
    __syncthreads();

    f32x4 acc[4][2];
#pragma unroll
    for (int rt = 0; rt < 4; rt++)
#pragma unroll
        for (int ct = 0; ct < 2; ct++) {
            float b = bs[(w * 2 + ct) * 16 + ll];
            acc[rt][ct] = (f32x4){b, b, b, b};
        }
#pragma unroll
    for (int kc = 0; kc < 12; kc++) {
        const unsigned short* Asrc = &A3[kc >> 2][0];
        int kcL = kc & 3;
        half8 af[4];
#pragma unroll
        for (int rt = 0; rt < 4; rt++) af[rt] = load_afrag(Asrc, rt * 16, ll, lg, kcL);
        half8 bf[2];
#pragma unroll
        for (int ct = 0; ct < 2; ct++)
            bf[ct] = *(const half8*)(Cp + ((size_t)(kc * 8 + w * 2 + ct) * 64 + l) * 8);
#pragma unroll
        for (int rt = 0; rt < 4; rt++)
#pragma unroll
            for (int ct = 0; ct < 2; ct++)
                acc[rt][ct] = __builtin_amdgcn_mfma_f32_16x16x32_f16(af[rt], bf[ct], acc[rt][ct], 0, 0, 0);
    }
#pragma unroll
    for (int rt = 0; rt < 4; rt++)
#pragma unroll
        for (int ct = 0; ct < 2; ct++)
#pragma unroll
            for (int r = 0; r < 4; r++) {
                int node = node0 + rt * 16 + (lg << 2) + r;
                if (node < NN) {
                    float v = acc[rt][ct][r];
                    v = v > 0.f ? v : 0.f;
                    h1[(size_t)node * FF + (w * 2 + ct) * 16 + ll] = (h16)v;
                }
            }
}

// ---------------- layer-2 combine + softmax (C=2) ----------------
__global__ void k_lout2(const h16* __restrict__ h1, const h16* __restrict__ n0,
                        const h16* __restrict__ n1, const float* __restrict__ wc2,
                        const float* __restrict__ b2s, float* __restrict__ out) {
    __shared__ float Wl[768];
    const int tid = threadIdx.x;
    for (int i = tid; i < 768; i += 256) Wl[i] = wc2[i];
    __syncthreads();
    const int node = blockIdx.x * 64 + (tid >> 2);
    const int q = tid & 3;
    float a0 = 0.f, a1 = 0.f;
    if (node < NN) {
        const h16* srcs[3] = {h1, n0, n1};
#pragma unroll
        for (int r3 = 0; r3 < 3; r3++) {
            const h16* sp = srcs[r3] + (size_t)node * FF + q * 32;
#pragma unroll
            for (int c4 = 0; c4 < 4; c4++) {
                half8 v = *(const half8*)(sp + c4 * 8);
#pragma unroll
                for (int i = 0; i < 8; i++) {
                    float xv = (float)v[i];
                    int k = r3 * 128 + q * 32 + c4 * 8 + i;
                    a0 += xv * Wl[k * 2];
                    a1 += xv * Wl[k * 2 + 1];
                }
            }
        }
    }
    a0 += __shfl_xor(a0, 1); a0 += __shfl_xor(a0, 2);
    a1 += __shfl_xor(a1, 1); a1 += __shfl_xor(a1, 2);
    if (q == 0 && node < NN) {
        a0 += b2s[0]; a1 += b2s[1];
        out[(size_t)node * 2]     = a0;
        out[(size_t)node * 2 + 1] = a1;
        float m = fmaxf(a0, a1);
        float e0 = __expf(a0 - m), e1 = __expf(a1 - m);
        float s = 1.f / (e0 + e1);
        out[40000 + (size_t)node * 2]     = e0 * s;
        out[40000 + (size_t)node * 2 + 1] = e1 * s;
    }
}

extern "C" void kernel_launch(void* const* d_in, const int* in_sizes, int n_in,
                              void* d_out, int out_size, void* d_ws, size_t ws_size,
                              hipStream_t stream) {
    const float* x     = (const float*)d_in[0];
    const int*   nbr   = (const int*)d_in[1];
    const int*   deg   = (const int*)d_in[2];
    const float* l1Wih = (const float*)d_in[3];
    const float* l1Whh = (const float*)d_in[4];
    const float* l1bih = (const float*)d_in[5];
    const float* l1bhh = (const float*)d_in[6];
    const float* l1Ws  = (const float*)d_in[7];
    const float* l1Wn  = (const float*)d_in[8];
    const float* l1b   = (const float*)d_in[9];
    const float* l2Wih = (const float*)d_in[10];
    const float* l2Whh = (const float*)d_in[11];
    const float* l2bih = (const float*)d_in[12];
    const float* l2bhh = (const float*)d_in[13];
    const float* l2Ws  = (const float*)d_in[14];
    const float* l2Wn  = (const float*)d_in[15];
    const float* l2b   = (const float*)d_in[16];

    char* ws = (char*)d_ws;
    h16*  x16   = (h16*)(ws + OFF_X);
    h16*  h1    = (h16*)(ws + OFF_H1);
    h16*  n1b   = (h16*)(ws + OFF_N1);
    h16*  n2b   = (h16*)(ws + OFF_N2);
    h16*  B1    = (h16*)(ws + OFF_B1);                 // sets 0,1 (layer1 e0,e1)
    h16*  B2    = (h16*)(ws + OFF_B1) + 2u * 131072u;  // sets 2,3 (layer2 e0,e1)
    h16*  Cp1   = (h16*)(ws + OFF_WC1);
    float* wc2  = (float*)(ws + OFF_WC2);
    float* bias1 = (float*)(ws + OFF_BI1);
    float* bias2 = (float*)(ws + OFF_BI2);
    float* bs1   = (float*)(ws + OFF_BS1);
    float* b2s   = (float*)(ws + OFF_B2S);

    k_cast_x    <<<dim3(1250), dim3(256), 0, stream>>>(x, x16, NN * FF);
    k_pack_gates<<<dim3(256),  dim3(256), 0, stream>>>(l1Wih, l1Whh, l2Wih, l2Whh, B1);
    k_pack_wc1  <<<dim3(24),   dim3(256), 0, stream>>>(l1Ws, l1Wn, Cp1);
    k_small     <<<dim3(8),    dim3(256), 0, stream>>>(l1bih, l1bhh, l2bih, l2bhh, l1b,
                                                       l2Ws, l2Wn, l2b,
                                                       bias1, bias2, bs1, wc2, b2s);

    k_lstm <<<dim3(313, 2), dim3(256), 0, stream>>>(x16, nbr, deg, B1, bias1, n1b);
    k_lout1<<<dim3(313),    dim3(256), 0, stream>>>(x16, n1b, n1b + (size_t)NN * FF, Cp1, bs1, h1);
    k_lstm <<<dim3(313, 2), dim3(256), 0, stream>>>(h1, nbr, deg, B2, bias2, n2b);
    k_lout2<<<dim3(313),    dim3(256), 0, stream>>>(h1, n2b, n2b + (size_t)NN * FF, wc2, b2s,
                                                    (float*)d_out);
}

// Round 2
// 2219.813 us; speedup vs baseline: 1.1451x; 1.1451x over previous
//
#include <hip/hip_runtime.h>
#include <stdint.h>

#define NN 20000
#define DD 16
#define FF 128
#define GG 512   // 4*F

typedef _Float16 h16;
typedef _Float16 half8 __attribute__((ext_vector_type(8)));
typedef float f32x4 __attribute__((ext_vector_type(4)));

// ---- workspace layout (bytes, all 256-aligned) ----
#define OFF_X    0u          // x_f16   [N][128]          5,120,000
#define OFF_H1   5120000u    // h1_f16  [N][128]          5,120,000
#define OFF_N1   10240000u   // n1buf   [2][N][128] f16  10,240,000
#define OFF_N2   20480000u   // n2buf   [2][N][128] f16  10,240,000
#define OFF_B1   30720000u   // Bpack   [4sets][8kc][32ct][64lane][8] f16
#define OFF_WC1  31768576u   // Cpack   [12][8][64][8] f16
#define OFF_WC2  31866880u   // Wcat2   [384][2] f32
#define OFF_BI1  31869952u   // bias1   [2][512] f32
#define OFF_BI2  31874048u   // bias2   [2][512] f32
#define OFF_BS1  31878144u   // bs1     [128] f32
#define OFF_B2S  31878656u   // b2s     [2] f32

__device__ __forceinline__ float sigm(float x)  { return __builtin_amdgcn_rcpf(1.f + __expf(-x)); }
__device__ __forceinline__ float tanh_(float x) { return 2.f * __builtin_amdgcn_rcpf(1.f + __expf(-2.f * x)) - 1.f; }

__device__ __forceinline__ void gload_lds16(const void* g, void* s) {
    __builtin_amdgcn_global_load_lds((const __attribute__((address_space(1))) void*)g,
                                     (__attribute__((address_space(3))) void*)s, 16, 0, 0);
}

// A-fragment loader from swizzled [64][128] f16 LDS tile.
// Fragment k-map (consistent with B pack): k = kcL*32 + (lg<<2) + (j&3) + 16*(j>>2)
__device__ __forceinline__ half8 load_afrag(const unsigned short* Asrc, int rowbase,
                                            int ll, int lg, int kcL) {
    int row = rowbase + ll;
    int sw  = (row & 7) << 4;
    int k0b = (kcL * 32 + (lg << 2)) * 2;
    const char* base = (const char*)Asrc + row * 256;
    uint2 lo = *(const uint2*)(base + (k0b ^ sw));
    uint2 hi = *(const uint2*)(base + ((k0b + 32) ^ sw));
    union { uint4 u; half8 h; } cv;
    cv.u = make_uint4(lo.x, lo.y, hi.x, hi.y);
    return cv.h;
}

// ---------------- prep kernels ----------------
__global__ void k_cast_x(const float* __restrict__ x, h16* __restrict__ xo, int n) {
    int i = blockIdx.x * blockDim.x + threadIdx.x;
    int base = i * 8;
    if (base >= n) return;
    const float4* p = (const float4*)(x + base);
    float4 a = p[0], b = p[1];
    half8 v = {(h16)a.x,(h16)a.y,(h16)a.z,(h16)a.w,(h16)b.x,(h16)b.y,(h16)b.z,(h16)b.w};
    *(half8*)(xo + base) = v;
}

// pack [x|h] gate weights into per-lane fragment order: [set][kc][ct][lane][8]
__global__ void k_pack_gates(const float* __restrict__ l1Wih, const float* __restrict__ l1Whh,
                             const float* __restrict__ l2Wih, const float* __restrict__ l2Whh,
                             h16* __restrict__ Bp) {
    int idx = blockIdx.x * 256 + threadIdx.x;      // 65536 total
    int set = idx >> 14;
    int rem = idx & 16383;
    int kc  = rem >> 11;
    int ct  = (rem >> 6) & 31;
    int l   = rem & 63;
    const float* Wih = (set < 2 ? l1Wih : l2Wih) + (size_t)(set & 1) * (FF * GG);
    const float* Whh = (set < 2 ? l1Whh : l2Whh) + (size_t)(set & 1) * (FF * GG);
    int col = ct * 16 + (l & 15);
    half8 v;
#pragma unroll
    for (int j = 0; j < 8; j++) {
        int k = kc * 32 + ((l >> 4) << 2) + (j & 3) + ((j >> 2) << 4);
        float val = (k < FF) ? Wih[k * GG + col] : Whh[(k - FF) * GG + col];
        v[j] = (h16)val;
    }
    *(half8*)(Bp + (size_t)idx * 8) = v;
}

// pack layer-1 combine weights: concat [x|n0|n1] (K=384) x 128, with 0.5 folded in
__global__ void k_pack_wc1(const float* __restrict__ Wself, const float* __restrict__ Wneigh,
                           h16* __restrict__ Cp) {
    int idx = blockIdx.x * 256 + threadIdx.x;      // 6144 total
    if (idx >= 6144) return;
    int kc = idx >> 9;
    int ct = (idx >> 6) & 7;
    int l  = idx & 63;
    int col = ct * 16 + (l & 15);
    half8 v;
#pragma unroll
    for (int j = 0; j < 8; j++) {
        int k = kc * 32 + ((l >> 4) << 2) + (j & 3) + ((j >> 2) << 4);
        float val;
        if (k < 128)      val = 0.5f * (Wself[k * 128 + col] + Wself[16384 + k * 128 + col]);
        else if (k < 256) val = 0.5f * Wneigh[(k - 128) * 128 + col];
        else              val = 0.5f * Wneigh[16384 + (k - 256) * 128 + col];
        v[j] = (h16)val;
    }
    *(half8*)(Cp + (size_t)idx * 8) = v;
}

__global__ void k_small(const float* __restrict__ l1bih, const float* __restrict__ l1bhh,
                        const float* __restrict__ l2bih, const float* __restrict__ l2bhh,
                        const float* __restrict__ l1b,  const float* __restrict__ l2Ws,
                        const float* __restrict__ l2Wn, const float* __restrict__ l2b,
                        float* __restrict__ bias1, float* __restrict__ bias2,
                        float* __restrict__ bs1,  float* __restrict__ wc2,
                        float* __restrict__ b2s) {
    int g = blockIdx.x * 256 + threadIdx.x;        // grid 8 -> 2048
    if (g < 1024) bias1[g] = l1bih[g] + l1bhh[g];
    else if (g < 2048) { int j = g - 1024; bias2[j] = l2bih[j] + l2bhh[j]; }
    if (g < 128) bs1[g] = 0.5f * (l1b[g] + l1b[128 + g]);
    if (g < 768) {
        int k = g >> 1, c = g & 1;
        float val;
        if (k < 128)      val = 0.5f * (l2Ws[k * 2 + c] + l2Ws[256 + k * 2 + c]);
        else if (k < 256) val = 0.5f * l2Wn[(k - 128) * 2 + c];
        else              val = 0.5f * l2Wn[256 + (k - 256) * 2 + c];
        wc2[g] = val;
    }
    if (g < 2) b2s[g] = 0.5f * (l2b[g] + l2b[2 + g]);
}

// ---------------- LSTM aggregation ----------------
// grid (313, 2e), block 512 (8 waves). 64 nodes/WG; wave w owns feature slice
// [w*16, w*16+16) across all 4 gates -> in-register cell update.
// Gather for step t+1 issued via global_load_lds (pre-swizzled source) at the
// top of step t into a double-buffered Ax -> gather latency off critical path.
__global__ __launch_bounds__(512, 4)
void k_lstm(const h16* __restrict__ src, const int* __restrict__ nbr_g,
            const int* __restrict__ deg_g, const h16* __restrict__ Bp_g,
            const float* __restrict__ bias_g, h16* __restrict__ out_g) {
    const int e = blockIdx.y;
    const int* nbr = nbr_g + (size_t)e * NN * DD;
    const int* deg = deg_g + (size_t)e * NN;
    const h16* Bp  = Bp_g + (size_t)e * (8 * 32 * 64 * 8);
    const float* bias = bias_g + e * GG;
    h16* outp = out_g + (size_t)e * NN * FF;

    __shared__ unsigned short Axb[2][64 * 128];   // double-buffered x_t tile (swizzled)
    __shared__ unsigned short Ah[64 * 128];       // h tile (swizzled)
    __shared__ int nbr_l[64 * DD];

    const int tid = threadIdx.x;
    const int l = tid & 63, w = tid >> 6;          // 8 waves
    const int lg = l >> 4, ll = l & 15;
    const int node0 = blockIdx.x * 64;

    // stage neighbor lists for this wave's gather rows (w*8 .. w*8+7); each wave
    // only ever READS its own rows -> no barrier needed between write and read.
    {
        int node = node0 + w * 8 + (l >> 3);
        int2 v = make_int2(0, 0);
        if (node < NN) v = *(const int2*)(nbr + (size_t)node * DD + ((l & 7) * 2));
        *(int2*)&nbr_l[(w * 8) * DD + l * 2] = v;
    }
    // zero Ah (16KB / 512 threads = 32B each)
    {
        uint4 z = make_uint4(0, 0, 0, 0);
        *(uint4*)&Ah[tid * 16] = z;
        *(uint4*)&Ah[tid * 16 + 8] = z;
    }

    unsigned int degr4[4];                    // 4x 8-bit degree fields (255 = OOB)
#pragma unroll
    for (int rt = 0; rt < 4; rt++) {
        unsigned int pk = 0;
#pragma unroll
        for (int r = 0; r < 4; r++) {
            int node = node0 + rt * 16 + (lg << 2) + r;
            int dv = (node < NN) ? deg[node] : 255;
            pk |= ((unsigned int)(dv & 255)) << (8 * r);
        }
        degr4[rt] = pk;
    }

    float biasr[4];
#pragma unroll
    for (int g = 0; g < 4; g++) biasr[g] = bias[(g * 8 + w) * 16 + ll];

    // deg==0 nodes output zeros
#pragma unroll
    for (int rt = 0; rt < 4; rt++)
#pragma unroll
        for (int r = 0; r < 4; r++)
            if (((degr4[rt] >> (8 * r)) & 255) == 0) {
                int node = node0 + rt * 16 + (lg << 2) + r;
                outp[(size_t)node * FF + w * 16 + ll] = (h16)0.f;
            }

    f32x4 cst[4];
#pragma unroll
    for (int rt = 0; rt < 4; rt++) cst[rt] = (f32x4){0.f, 0.f, 0.f, 0.f};

    // async gather: 2 instrs/wave, 4 rows each (64 lanes x 16B = 1KB).
    // LDS dest is linear (wave-uniform base + lane*16); swizzle applied by
    // XOR-permuting the per-lane GLOBAL source column (involution).
    auto do_gather = [&](int t1, unsigned short* dst) {
#pragma unroll
        for (int i = 0; i < 2; i++) {
            int row = w * 8 + i * 4 + lg;
            int idx = nbr_l[row * DD + t1];
            const char* gp = (const char*)(src + (size_t)idx * FF)
                             + ((ll * 16) ^ (((i * 4 + lg) & 7) << 4));
            gload_lds16(gp, &dst[(w * 8 + i * 4) * 128]);
        }
    };

    do_gather(0, &Axb[0][0]);
    __syncthreads();   // drains vmcnt -> Axb[0] ready; Ah zeros visible

#pragma unroll 1
    for (int t = 0; t < DD; t++) {
        const unsigned short* AxCur = &Axb[t & 1][0];
        unsigned short* AxNxt = &Axb[(t + 1) & 1][0];
        if (t + 1 < DD) do_gather(t + 1, AxNxt);   // a full step of compute to hide

        f32x4 acc[4][4];
#pragma unroll
        for (int rt = 0; rt < 4; rt++)
#pragma unroll
            for (int g = 0; g < 4; g++)
                acc[rt][g] = (f32x4){biasr[g], biasr[g], biasr[g], biasr[g]};

#pragma unroll
        for (int kc = 0; kc < 8; kc++) {
            const unsigned short* Asrc = (kc < 4) ? AxCur : Ah;
            const int kcL = kc & 3;
            half8 bf[4];
#pragma unroll
            for (int g = 0; g < 4; g++)
                bf[g] = *(const half8*)(Bp + ((size_t)(kc * 32 + g * 8 + w) * 64 + l) * 8);
#pragma unroll
            for (int rt = 0; rt < 4; rt++) {
                half8 af = load_afrag(Asrc, rt * 16, ll, lg, kcL);
#pragma unroll
                for (int g = 0; g < 4; g++)
                    acc[rt][g] = __builtin_amdgcn_mfma_f32_16x16x32_f16(af, bf[g], acc[rt][g], 0, 0, 0);
            }
        }

        // in-register LSTM cell update; capture h at final active step
        unsigned short hb[4][4];
#pragma unroll
        for (int rt = 0; rt < 4; rt++)
#pragma unroll
            for (int r = 0; r < 4; r++) {
                int dfield = (degr4[rt] >> (8 * r)) & 255;
                float iv = sigm(acc[rt][0][r]);
                float fv = sigm(acc[rt][1][r]);
                float gv = tanh_(acc[rt][2][r]);
                float ov = sigm(acc[rt][3][r]);
                float c_ = fv * cst[rt][r] + iv * gv;
                float h_ = ov * tanh_(c_);
                cst[rt][r] = c_;
                h16 hh = (h16)h_;
                hb[rt][r] = __builtin_bit_cast(unsigned short, hh);
                if (t + 1 == dfield) {
                    int node = node0 + rt * 16 + (lg << 2) + r;
                    outp[(size_t)node * FF + w * 16 + ll] = hh;
                }
            }

        __syncthreads();   // all waves done reading Ah / AxCur

#pragma unroll
        for (int rt = 0; rt < 4; rt++)
#pragma unroll
            for (int r = 0; r < 4; r++) {
                int row = rt * 16 + (lg << 2) + r;
                int colb = (w * 16 + ll) * 2;
                *(unsigned short*)((char*)Ah + row * 256 + (colb ^ ((row & 7) << 4))) = hb[rt][r];
            }

        __syncthreads();   // Ah writes + AxNxt gather (vmcnt drained) visible
    }
}

// ---------------- layer-1 combine: h1 = relu([x|n0|n1] @ Wcat1 + bs1) ----------------
__global__ __launch_bounds__(256, 4)
void k_lout1(const h16* __restrict__ x16, const h16* __restrict__ n0,
             const h16* __restrict__ n1, const h16* __restrict__ Cp,
             const float* __restrict__ bs, h16* __restrict__ h1) {
    __shared__ unsigned short A3[3][64 * 128];
    const int tid = threadIdx.x;
    const int l = tid & 63, w = tid >> 6, lg = l >> 4, ll = l & 15;
    const int node0 = blockIdx.x * 64;
    const h16* srcs[3] = {x16, n0, n1};
#pragma unroll
    for (int r3 = 0; r3 < 3; r3++)
#pragma unroll
        for (int k = 0; k < 4; k++) {
            int row = w * 16 + k * 4 + lg;
            int node = node0 + row;
            uint4 v = (node < NN) ? *(const uint4*)(srcs[r3] + (size_t)node * FF + ll * 8)
                                  : make_uint4(0, 0, 0, 0);
            *(uint4*)((char*)&A3[r3][0] + row * 256 + ((ll * 16) ^ ((row & 7) << 4))) = v;
        }
    __syncthreads();

    f32x4 acc[4][2];
#pragma unroll
    for (int rt = 0; rt < 4; rt++)
#pragma unroll
        for (int ct = 0; ct < 2; ct++) {
            float b = bs[(w * 2 + ct) * 16 + ll];
            acc[rt][ct] = (f32x4){b, b, b, b};
        }
#pragma unroll
    for (int kc = 0; kc < 12; kc++) {
        const unsigned short* Asrc = &A3[kc >> 2][0];
        int kcL = kc & 3;
        half8 af[4];
#pragma unroll
        for (int rt = 0; rt < 4; rt++) af[rt] = load_afrag(Asrc, rt * 16, ll, lg, kcL);
        half8 bf[2];
#pragma unroll
        for (int ct = 0; ct < 2; ct++)
            bf[ct] = *(const half8*)(Cp + ((size_t)(kc * 8 + w * 2 + ct) * 64 + l) * 8);
#pragma unroll
        for (int rt = 0; rt < 4; rt++)
#pragma unroll
            for (int ct = 0; ct < 2; ct++)
                acc[rt][ct] = __builtin_amdgcn_mfma_f32_16x16x32_f16(af[rt], bf[ct], acc[rt][ct], 0, 0, 0);
    }
#pragma unroll
    for (int rt = 0; rt < 4; rt++)
#pragma unroll
        for (int ct = 0; ct < 2; ct++)
#pragma unroll
            for (int r = 0; r < 4; r++) {
                int node = node0 + rt * 16 + (lg << 2) + r;
                if (node < NN) {
                    float v = acc[rt][ct][r];
                    v = v > 0.f ? v : 0.f;
                    h1[(size_t)node * FF + (w * 2 + ct) * 16 + ll] = (h16)v;
                }
            }
}

// ---------------- layer-2 combine + softmax (C=2) ----------------
__global__ void k_lout2(const h16* __restrict__ h1, const h16* __restrict__ n0,
                        const h16* __restrict__ n1, const float* __restrict__ wc2,
                        const float* __restrict__ b2s, float* __restrict__ out) {
    __shared__ float Wl[768];
    const int tid = threadIdx.x;
    for (int i = tid; i < 768; i += 256) Wl[i] = wc2[i];
    __syncthreads();
    const int node = blockIdx.x * 64 + (tid >> 2);
    const int q = tid & 3;
    float a0 = 0.f, a1 = 0.f;
    if (node < NN) {
        const h16* srcs[3] = {h1, n0, n1};
#pragma unroll
        for (int r3 = 0; r3 < 3; r3++) {
            const h16* sp = srcs[r3] + (size_t)node * FF + q * 32;
#pragma unroll
            for (int c4 = 0; c4 < 4; c4++) {
                half8 v = *(const half8*)(sp + c4 * 8);
#pragma unroll
                for (int i = 0; i < 8; i++) {
                    float xv = (float)v[i];
                    int k = r3 * 128 + q * 32 + c4 * 8 + i;
                    a0 += xv * Wl[k * 2];
                    a1 += xv * Wl[k * 2 + 1];
                }
            }
        }
    }
    a0 += __shfl_xor(a0, 1); a0 += __shfl_xor(a0, 2);
    a1 += __shfl_xor(a1, 1); a1 += __shfl_xor(a1, 2);
    if (q == 0 && node < NN) {
        a0 += b2s[0]; a1 += b2s[1];
        out[(size_t)node * 2]     = a0;
        out[(size_t)node * 2 + 1] = a1;
        float m = fmaxf(a0, a1);
        float e0 = __expf(a0 - m), e1 = __expf(a1 - m);
        float s = 1.f / (e0 + e1);
        out[40000 + (size_t)node * 2]     = e0 * s;
        out[40000 + (size_t)node * 2 + 1] = e1 * s;
    }
}

extern "C" void kernel_launch(void* const* d_in, const int* in_sizes, int n_in,
                              void* d_out, int out_size, void* d_ws, size_t ws_size,
                              hipStream_t stream) {
    const float* x     = (const float*)d_in[0];
    const int*   nbr   = (const int*)d_in[1];
    const int*   deg   = (const int*)d_in[2];
    const float* l1Wih = (const float*)d_in[3];
    const float* l1Whh = (const float*)d_in[4];
    const float* l1bih = (const float*)d_in[5];
    const float* l1bhh = (const float*)d_in[6];
    const float* l1Ws  = (const float*)d_in[7];
    const float* l1Wn  = (const float*)d_in[8];
    const float* l1b   = (const float*)d_in[9];
    const float* l2Wih = (const float*)d_in[10];
    const float* l2Whh = (const float*)d_in[11];
    const float* l2bih = (const float*)d_in[12];
    const float* l2bhh = (const float*)d_in[13];
    const float* l2Ws  = (const float*)d_in[14];
    const float* l2Wn  = (const float*)d_in[15];
    const float* l2b   = (const float*)d_in[16];

    char* ws = (char*)d_ws;
    h16*  x16   = (h16*)(ws + OFF_X);
    h16*  h1    = (h16*)(ws + OFF_H1);
    h16*  n1b   = (h16*)(ws + OFF_N1);
    h16*  n2b   = (h16*)(ws + OFF_N2);
    h16*  B1    = (h16*)(ws + OFF_B1);                 // sets 0,1 (layer1 e0,e1)
    h16*  B2    = (h16*)(ws + OFF_B1) + 2u * 131072u;  // sets 2,3 (layer2 e0,e1)
    h16*  Cp1   = (h16*)(ws + OFF_WC1);
    float* wc2  = (float*)(ws + OFF_WC2);
    float* bias1 = (float*)(ws + OFF_BI1);
    float* bias2 = (float*)(ws + OFF_BI2);
    float* bs1   = (float*)(ws + OFF_BS1);
    float* b2s   = (float*)(ws + OFF_B2S);

    k_cast_x    <<<dim3(1250), dim3(256), 0, stream>>>(x, x16, NN * FF);
    k_pack_gates<<<dim3(256),  dim3(256), 0, stream>>>(l1Wih, l1Whh, l2Wih, l2Whh, B1);
    k_pack_wc1  <<<dim3(24),   dim3(256), 0, stream>>>(l1Ws, l1Wn, Cp1);
    k_small     <<<dim3(8),    dim3(256), 0, stream>>>(l1bih, l1bhh, l2bih, l2bhh, l1b,
                                                       l2Ws, l2Wn, l2b,
                                                       bias1, bias2, bs1, wc2, b2s);

    k_lstm <<<dim3(313, 2), dim3(512), 0, stream>>>(x16, nbr, deg, B1, bias1, n1b);
    k_lout1<<<dim3(313),    dim3(256), 0, stream>>>(x16, n1b, n1b + (size_t)NN * FF, Cp1, bs1, h1);
    k_lstm <<<dim3(313, 2), dim3(512), 0, stream>>>(h1, nbr, deg, B2, bias2, n2b);
    k_lout2<<<dim3(313),    dim3(256), 0, stream>>>(h1, n2b, n2b + (size_t)NN * FF, wc2, b2s,
                                                    (float*)d_out);
}